// Round 2
// baseline (750.985 us; speedup 1.0000x reference)
//
#include <hip/hip_runtime.h>
#include <hip/hip_bf16.h>
#include <cmath>

// Problem constants
constexpr int B  = 4;
constexpr int T  = 2048;
constexpr int C  = 768;
constexpr int H  = 12;
constexpr int Dh = 64;
constexpr int M  = B * T;          // 8192
constexpr int NQKV = 3 * C;        // 2304 fused QKV output width
constexpr int WS2  = C * C;        // 589824 elems per weight matrix

typedef short bf16x8 __attribute__((ext_vector_type(8)));
typedef short bf16x4 __attribute__((ext_vector_type(4)));
typedef float f32x4  __attribute__((ext_vector_type(4)));
typedef float f32x16 __attribute__((ext_vector_type(16)));

// softmax scale folded into Q at GEMM epilogue: (1/sqrt(Dh)) * log2(e)
constexpr float SOFT_SCALE = 0.18033688011112042f;

__device__ inline short f2bf(float f) {   // fp32 -> bf16 round-nearest-even
    unsigned u = __float_as_uint(f);
    u += 0x7fffu + ((u >> 16) & 1u);
    return (short)(u >> 16);
}

__device__ inline unsigned pk_bf16(float a, float b) {  // packed pair (RNE)
    __hip_bfloat162 h = __float22bfloat162_rn(float2{a, b});
    return *(unsigned*)&h;
}

__device__ inline bf16x8 mk8(unsigned a, unsigned b, unsigned c, unsigned d) {
    union { unsigned u[4]; bf16x8 v; } x;
    x.u[0] = a; x.u[1] = b; x.u[2] = c; x.u[3] = d;
    return x.v;
}

// global(AS1) -> LDS(AS3) 16-byte async copy; HW writes ldsbase + lane*16.
typedef const __attribute__((address_space(1))) unsigned GU;
typedef __attribute__((address_space(3))) unsigned LU;
__device__ inline void async_copy16(const void* g, void* l) {
    __builtin_amdgcn_global_load_lds((GU*)g, (LU*)l, 16, 0, 0);
}

// ---------------------------------------------------------------------------
// Fused fp32 -> bf16 convert for x + all four weights (one launch).
// ---------------------------------------------------------------------------
constexpr size_t XE = (size_t)M * C;                // 6291456
constexpr size_t CV_TOTAL = XE + 4 * (size_t)WS2;   // 8650752

__global__ __launch_bounds__(256)
void convert_all(const float* __restrict__ x,  const float* __restrict__ Wq,
                 const float* __restrict__ Wk, const float* __restrict__ Wv,
                 const float* __restrict__ Wp,
                 short* __restrict__ xb, short* __restrict__ Wqkv,
                 short* __restrict__ Wpb) {
    size_t i = ((size_t)blockIdx.x * 256 + threadIdx.x) * 4;
    const float* src; short* dst; size_t off;
    if (i < XE)                        { src = x;  dst = xb;            off = i; }
    else if (i < XE + WS2)             { src = Wq; dst = Wqkv;          off = i - XE; }
    else if (i < XE + 2 * (size_t)WS2) { src = Wk; dst = Wqkv + WS2;    off = i - XE - WS2; }
    else if (i < XE + 3 * (size_t)WS2) { src = Wv; dst = Wqkv + 2 * WS2; off = i - XE - 2 * (size_t)WS2; }
    else                               { src = Wp; dst = Wpb;           off = i - XE - 3 * (size_t)WS2; }
    float4 v = *(const float4*)(src + off);
    bf16x4 o; o[0] = f2bf(v.x); o[1] = f2bf(v.y); o[2] = f2bf(v.z); o[3] = f2bf(v.w);
    *(bf16x4*)(dst + off) = o;
}

// ---------------------------------------------------------------------------
// bf16 MFMA GEMM: Y[M,N] = A[M,K] @ W[N,K]^T (+bias).
// QSCALE: multiply the first C output columns (the Q block of fused QKV) by
// SOFT_SCALE so attn's exp2 needs no per-element multiply.
// ---------------------------------------------------------------------------
constexpr int BM = 128;

template<int BN_, int WMW, int WNW, int OUT_BF16, int QSCALE>
__global__ __launch_bounds__(256)
void gemm_bt(const short* __restrict__ A, const short* __restrict__ W,
             const float* __restrict__ bias0, const float* __restrict__ bias1,
             const float* __restrict__ bias2,
             void* __restrict__ Yv, int Ndim, int Kdim) {
    constexpr int MT  = BM / WMW / 16;
    constexpr int NT  = BN_ / WNW / 16;
    constexpr int NCH = (BM + BN_) / 16;     // 16-row chunks per k-half

    __shared__ short As[2][BM * 32];
    __shared__ short Bs[2][BN_ * 32];

    const int tid  = threadIdx.x;
    const int wave = tid >> 6;
    const int lane = tid & 63;
    const int li   = lane & 15;
    const int quad = lane >> 4;
    const int wm   = wave % WMW;
    const int wn   = wave / WMW;
    const int m0   = blockIdx.y * BM;
    const int n0   = blockIdx.x * BN_;

    f32x4 acc[MT][NT];
    #pragma unroll
    for (int i = 0; i < MT; ++i)
        #pragma unroll
        for (int j = 0; j < NT; ++j)
            acc[i][j] = (f32x4){0.f, 0.f, 0.f, 0.f};

    const int lrow = lane >> 2;          // 0..15 row within 16-row chunk
    const int lkof = (lane & 3) * 8;     // 16B chunk within 32-short half-row

    for (int k0 = 0; k0 < Kdim; k0 += 64) {
        __syncthreads();
        #pragma unroll
        for (int h = 0; h < 2; ++h)
            #pragma unroll
            for (int ii = 0; ii < NCH / 4; ++ii) {
                int c = ii * 4 + wave;
                if (c < BM / 16)
                    async_copy16(A + (size_t)(m0 + c * 16 + lrow) * Kdim
                                   + k0 + h * 32 + lkof,
                                 &As[h][c * 512]);
                else
                    async_copy16(W + (size_t)(n0 + (c - BM / 16) * 16 + lrow) * Kdim
                                   + k0 + h * 32 + lkof,
                                 &Bs[h][(c - BM / 16) * 512]);
            }
        __syncthreads();

        #pragma unroll
        for (int h = 0; h < 2; ++h) {
            bf16x8 af[MT], bfr[NT];
            #pragma unroll
            for (int t = 0; t < MT; ++t)
                af[t] = *(const bf16x8*)&As[h][(wm * MT * 16 + t * 16 + li) * 32 + quad * 8];
            #pragma unroll
            for (int t = 0; t < NT; ++t)
                bfr[t] = *(const bf16x8*)&Bs[h][(wn * NT * 16 + t * 16 + li) * 32 + quad * 8];
            #pragma unroll
            for (int i = 0; i < MT; ++i)
                #pragma unroll
                for (int j = 0; j < NT; ++j)
                    acc[i][j] = __builtin_amdgcn_mfma_f32_16x16x32_bf16(
                        af[i], bfr[j], acc[i][j], 0, 0, 0);
        }
    }

    float bb[NT];
    #pragma unroll
    for (int nt = 0; nt < NT; ++nt) bb[nt] = 0.f;
    if (bias0) {
        int s = n0 / C;
        const float* bp = (s == 0) ? bias0 : ((s == 1) ? bias1 : bias2);
        int nb = n0 % C;
        #pragma unroll
        for (int nt = 0; nt < NT; ++nt)
            bb[nt] = bp[nb + wn * NT * 16 + nt * 16 + li];
    }

    #pragma unroll
    for (int mt = 0; mt < MT; ++mt)
        #pragma unroll
        for (int nt = 0; nt < NT; ++nt)
            #pragma unroll
            for (int r = 0; r < 4; ++r) {
                int row = m0 + wm * MT * 16 + mt * 16 + quad * 4 + r;
                int col = n0 + wn * NT * 16 + nt * 16 + li;
                float v = acc[mt][nt][r] + bb[nt];
                if constexpr (QSCALE) {
                    if (n0 < C) v *= SOFT_SCALE;   // wave-uniform branch
                }
                if constexpr (OUT_BF16)
                    ((short*)Yv)[(size_t)row * Ndim + col] = f2bf(v);
                else
                    ((float*)Yv)[(size_t)row * Ndim + col] = v;
            }
}

// ---------------------------------------------------------------------------
// MFMA flash attention, 32x32x16, in-register softmax, 2-way SPLIT-K.
//
// 512 threads = 8 waves: wave w -> q-subtile (w&3, 32 rows), k-half (w>>2).
// Valid because this softmax has NO running max: oacc/lacc are pure sums
// over k, so the two k-halves just add at the end (LDS reduction).
// Occupancy: 768 blocks -> 3 blocks/CU x 8 waves = 6 waves/SIMD (was 3).
// Staging: two independent k-streams (tid>>8) into disjoint LDS regions
// between the same barrier pair; per-block staged tokens unchanged (2048).
// LDS: K0|K1|Vt0|Vt1 = 36864 B, overlaid by 50176 B reduction buffer
// (stride 49 floats, conflict-free) -> 50176 B/block, 3 blocks/CU fits.
// ---------------------------------------------------------------------------
constexpr int QT   = 128;
constexpr int KTT  = 64;
constexpr int LSTR = 72;
constexpr int QS   = NQKV;
constexpr int KHT  = T / 2;        // 1024 k-tokens per k-half

__global__ __launch_bounds__(512, 6)
void attn_fwd(const short* __restrict__ QKV, short* __restrict__ O) {
    __shared__ short smem[25088];   // 50176 B: staging (36864) U reduction

    const int tid  = threadIdx.x;
    const int wave = tid >> 6;          // 0..7
    const int lane = tid & 63;
    const int r31  = lane & 31;
    const int hi   = lane >> 5;
    const int qs   = wave & 3;          // q sub-tile within block
    const int kh   = wave >> 2;         // k half (compute role)
    const int strm = tid >> 8;          // k-stream (staging role)
    const int t8   = tid & 255;
    const int b    = blockIdx.z;
    const int h    = blockIdx.y;
    const int qrow = blockIdx.x * QT + qs * 32;

    short* KsS = smem + strm * 4608;            // staging: K tile 64 x 72
    short* VtS = smem + 9216 + strm * 4608;     // staging: V^T tile 64 x 72
    const short* KsC = smem + kh * 4608;        // compute
    const short* VtC = smem + 9216 + kh * 4608;

    const short* Qg = QKV + (size_t)(b * T) * QS + h * Dh;
    const short* Kg = QKV + (size_t)(b * T) * QS + C + h * Dh;
    const short* Vg = QKV + (size_t)(b * T) * QS + 2 * C + h * Dh;

    // Q B-fragments: lane holds Q[qrow + (lane&31)][k = f*16 + hi*8 .. +7]
    bf16x8 qf[4];
    #pragma unroll
    for (int f = 0; f < 4; ++f)
        qf[f] = *(const bf16x8*)(Qg + (size_t)(qrow + r31) * QS + f * 16 + hi * 8);

    bf16x8 ones;
    #pragma unroll
    for (int i = 0; i < 8; ++i) ones[i] = (short)0x3F80;

    f32x16 oacc0 = (f32x16)(0.f);
    f32x16 oacc1 = (f32x16)(0.f);
    f32x16 lacc  = (f32x16)(0.f);

    // staging thread roles within the 256-thread stream group
    const int ktok = t8 >> 3;          // 0..31
    const int kch  = t8 & 7;
    const int vd2  = (t8 & 31) * 2;
    const int vg   = t8 >> 5;          // 0..7
    const int tbS  = strm * KHT;       // staging token base

    int4 kpre[2];
    unsigned vpre[8];
    kpre[0] = *(const int4*)(Kg + (size_t)(tbS + ktok)      * QS + kch * 8);
    kpre[1] = *(const int4*)(Kg + (size_t)(tbS + ktok + 32) * QS + kch * 8);
    #pragma unroll
    for (int t2 = 0; t2 < 8; ++t2)
        vpre[t2] = *(const unsigned*)(Vg + (size_t)(tbS + vg * 8 + t2) * QS + vd2);

    for (int ktl = 0; ktl < KHT; ktl += KTT) {
        __syncthreads();

        *(int4*)&KsS[ktok * LSTR + kch * 8]        = kpre[0];
        *(int4*)&KsS[(ktok + 32) * LSTR + kch * 8] = kpre[1];
        {
            unsigned lo[4], hh[4];
            #pragma unroll
            for (int j = 0; j < 4; ++j) {
                lo[j] = __builtin_amdgcn_perm(vpre[2 * j + 1], vpre[2 * j], 0x05040100u);
                hh[j] = __builtin_amdgcn_perm(vpre[2 * j + 1], vpre[2 * j], 0x07060302u);
            }
            *(int4*)&VtS[vd2 * LSTR + vg * 8]       = make_int4(lo[0], lo[1], lo[2], lo[3]);
            *(int4*)&VtS[(vd2 + 1) * LSTR + vg * 8] = make_int4(hh[0], hh[1], hh[2], hh[3]);
        }
        __syncthreads();

        if (ktl + KTT < KHT) {
            const size_t nb = tbS + ktl + KTT;
            kpre[0] = *(const int4*)(Kg + (nb + ktok)      * QS + kch * 8);
            kpre[1] = *(const int4*)(Kg + (nb + ktok + 32) * QS + kch * 8);
            #pragma unroll
            for (int t2 = 0; t2 < 8; ++t2)
                vpre[t2] = *(const unsigned*)(Vg + (nb + vg * 8 + t2) * QS + vd2);
        }

        // ---- QK^T: S[k][q] for this wave's 64-token tile ----
        f32x16 st0 = (f32x16)(0.f);
        f32x16 st1 = (f32x16)(0.f);
        __builtin_amdgcn_s_setprio(1);
        #pragma unroll
        for (int f = 0; f < 4; ++f) {
            bf16x8 k0 = *(const bf16x8*)&KsC[(r31)      * LSTR + f * 16 + hi * 8];
            bf16x8 k1 = *(const bf16x8*)&KsC[(32 + r31) * LSTR + f * 16 + hi * 8];
            st0 = __builtin_amdgcn_mfma_f32_32x32x16_bf16(k0, qf[f], st0, 0, 0, 0);
            st1 = __builtin_amdgcn_mfma_f32_32x32x16_bf16(k1, qf[f], st1, 0, 0, 0);
        }
        __builtin_amdgcn_s_setprio(0);

        // ---- per 32-token k-block: exp2 -> bf16 frags (in reg) -> PV ----
        #pragma unroll
        for (int kb = 0; kb < 2; ++kb) {
            f32x16 s = kb ? st1 : st0;          // kb is unroll-constant
            unsigned d[8];
            #pragma unroll
            for (int j = 0; j < 8; ++j) {
                float pa = __builtin_amdgcn_exp2f(s[2 * j]);
                float pb = __builtin_amdgcn_exp2f(s[2 * j + 1]);
                d[j] = pk_bf16(pa, pb);
            }
            // redistribute across lane^32 partners
            auto s02 = __builtin_amdgcn_permlane32_swap(d[0], d[2], false, false);
            auto s13 = __builtin_amdgcn_permlane32_swap(d[1], d[3], false, false);
            auto s46 = __builtin_amdgcn_permlane32_swap(d[4], d[6], false, false);
            auto s57 = __builtin_amdgcn_permlane32_swap(d[5], d[7], false, false);
            bf16x8 pf0 = mk8(s02[0], s13[0], s02[1], s13[1]);  // k = kb*32 + 0..15
            bf16x8 pf1 = mk8(s46[0], s57[0], s46[1], s57[1]);  // k = kb*32 + 16..31

            __builtin_amdgcn_s_setprio(1);
            lacc = __builtin_amdgcn_mfma_f32_32x32x16_bf16(pf0, ones, lacc, 0, 0, 0);
            lacc = __builtin_amdgcn_mfma_f32_32x32x16_bf16(pf1, ones, lacc, 0, 0, 0);

            bf16x8 v00 = *(const bf16x8*)&VtC[(r31)      * LSTR + kb * 32 + hi * 8];
            bf16x8 v01 = *(const bf16x8*)&VtC[(r31)      * LSTR + kb * 32 + 16 + hi * 8];
            bf16x8 v10 = *(const bf16x8*)&VtC[(32 + r31) * LSTR + kb * 32 + hi * 8];
            bf16x8 v11 = *(const bf16x8*)&VtC[(32 + r31) * LSTR + kb * 32 + 16 + hi * 8];
            oacc0 = __builtin_amdgcn_mfma_f32_32x32x16_bf16(pf0, v00, oacc0, 0, 0, 0);
            oacc0 = __builtin_amdgcn_mfma_f32_32x32x16_bf16(pf1, v01, oacc0, 0, 0, 0);
            oacc1 = __builtin_amdgcn_mfma_f32_32x32x16_bf16(pf0, v10, oacc1, 0, 0, 0);
            oacc1 = __builtin_amdgcn_mfma_f32_32x32x16_bf16(pf1, v11, oacc1, 0, 0, 0);
            __builtin_amdgcn_s_setprio(0);
        }
    }

    // ---- split-K combine: k-half 1 dumps partials to LDS, half 0 adds ----
    __syncthreads();                    // all K/V LDS reads done
    float* red = (float*)smem;
    if (kh == 1) {
        int base = ((wave - 4) * 64 + lane) * 49;   // stride 49: conflict-free
        #pragma unroll
        for (int r = 0; r < 16; ++r) {
            red[base + r]      = oacc0[r];
            red[base + 16 + r] = oacc1[r];
            red[base + 32 + r] = lacc[r];
        }
    }
    __syncthreads();
    if (kh == 0) {
        int base = (wave * 64 + lane) * 49;
        #pragma unroll
        for (int r = 0; r < 16; ++r) {
            float o0 = oacc0[r] + red[base + r];
            float o1 = oacc1[r] + red[base + 16 + r];
            float l  = lacc[r]  + red[base + 32 + r];
            float inv = 1.0f / l;
            int row = (r & 3) + 8 * (r >> 2) + 4 * hi;
            short* op = O + (size_t)(b * T + qrow + row) * C + h * Dh + r31;
            op[0]  = f2bf(o0 * inv);
            op[32] = f2bf(o1 * inv);
        }
    }
}

// ---------------------------------------------------------------------------
// Launch
// ---------------------------------------------------------------------------
extern "C" void kernel_launch(void* const* d_in, const int* in_sizes, int n_in,
                              void* d_out, int out_size, void* d_ws, size_t ws_size,
                              hipStream_t stream) {
    (void)in_sizes; (void)n_in; (void)out_size; (void)ws_size;

    const float* x  = (const float*)d_in[0];
    const float* Wq = (const float*)d_in[1];
    const float* bq = (const float*)d_in[2];
    const float* Wk = (const float*)d_in[3];
    const float* bk = (const float*)d_in[4];
    const float* Wv = (const float*)d_in[5];
    const float* bv = (const float*)d_in[6];
    const float* Wp = (const float*)d_in[7];
    float* out = (float*)d_out;

    short* xb    = (short*)d_ws;                 // [M][C]      bf16
    short* Wqkv  = xb + (size_t)M * C;           // [2304][768] bf16
    short* Wpb   = Wqkv + 3 * (size_t)WS2;       // [768][768]  bf16
    short* QKVb  = Wpb + (size_t)WS2;            // [M][2304]   bf16 (Q pre-scaled)
    short* AOb   = QKVb + (size_t)M * NQKV;      // [M][C]      bf16

    convert_all<<<dim3(CV_TOTAL / 1024), 256, 0, stream>>>(
        x, Wq, Wk, Wv, Wp, xb, Wqkv, Wpb);

    // Fused QKV projection: [8192 x 2304], Q columns scaled by SOFT_SCALE
    gemm_bt<128, 2, 2, 1, 1><<<dim3(NQKV / 128, M / BM), 256, 0, stream>>>(
        xb, Wqkv, bq, bk, bv, QKVb, NQKV, C);

    attn_fwd<<<dim3(T / QT, H, B), 512, 0, stream>>>(QKVb, AOb);

    // Output projection: [8192 x 768] fp32 out
    gemm_bt<64, 4, 1, 0, 0><<<dim3(C / 64, M / BM), 256, 0, stream>>>(
        AOb, Wpb, nullptr, nullptr, nullptr, out, C, C);
}

// Round 4
// 244.908 us; speedup vs baseline: 3.0664x; 3.0664x over previous
//
#include <hip/hip_runtime.h>
#include <hip/hip_bf16.h>
#include <cmath>

// Problem constants
constexpr int B  = 4;
constexpr int T  = 2048;
constexpr int C  = 768;
constexpr int H  = 12;
constexpr int Dh = 64;
constexpr int M  = B * T;          // 8192
constexpr int NQKV = 3 * C;        // 2304 fused QKV output width
constexpr int WS2  = C * C;        // 589824 elems per weight matrix

typedef short bf16x8 __attribute__((ext_vector_type(8)));
typedef short bf16x4 __attribute__((ext_vector_type(4)));
typedef float f32x4  __attribute__((ext_vector_type(4)));
typedef float f32x16 __attribute__((ext_vector_type(16)));

// softmax scale folded into Q at GEMM epilogue: (1/sqrt(Dh)) * log2(e)
constexpr float SOFT_SCALE = 0.18033688011112042f;

__device__ inline short f2bf(float f) {   // fp32 -> bf16 round-nearest-even
    unsigned u = __float_as_uint(f);
    u += 0x7fffu + ((u >> 16) & 1u);
    return (short)(u >> 16);
}

__device__ inline unsigned pk_bf16(float a, float b) {  // packed pair (RNE)
    __hip_bfloat162 h = __float22bfloat162_rn(float2{a, b});
    return *(unsigned*)&h;
}

__device__ inline bf16x8 mk8(unsigned a, unsigned b, unsigned c, unsigned d) {
    union { unsigned u[4]; bf16x8 v; } x;
    x.u[0] = a; x.u[1] = b; x.u[2] = c; x.u[3] = d;
    return x.v;
}

// global(AS1) -> LDS(AS3) 16-byte async copy; HW writes ldsbase + lane*16.
typedef const __attribute__((address_space(1))) unsigned GU;
typedef __attribute__((address_space(3))) unsigned LU;
__device__ inline void async_copy16(const void* g, void* l) {
    __builtin_amdgcn_global_load_lds((GU*)g, (LU*)l, 16, 0, 0);
}

// ---------------------------------------------------------------------------
// Fused fp32 -> bf16 convert for x + all four weights (one launch).
// ---------------------------------------------------------------------------
constexpr size_t XE = (size_t)M * C;                // 6291456
constexpr size_t CV_TOTAL = XE + 4 * (size_t)WS2;   // 8650752

__global__ __launch_bounds__(256)
void convert_all(const float* __restrict__ x,  const float* __restrict__ Wq,
                 const float* __restrict__ Wk, const float* __restrict__ Wv,
                 const float* __restrict__ Wp,
                 short* __restrict__ xb, short* __restrict__ Wqkv,
                 short* __restrict__ Wpb) {
    size_t i = ((size_t)blockIdx.x * 256 + threadIdx.x) * 4;
    const float* src; short* dst; size_t off;
    if (i < XE)                        { src = x;  dst = xb;            off = i; }
    else if (i < XE + WS2)             { src = Wq; dst = Wqkv;          off = i - XE; }
    else if (i < XE + 2 * (size_t)WS2) { src = Wk; dst = Wqkv + WS2;    off = i - XE - WS2; }
    else if (i < XE + 3 * (size_t)WS2) { src = Wv; dst = Wqkv + 2 * WS2; off = i - XE - 2 * (size_t)WS2; }
    else                               { src = Wp; dst = Wpb;           off = i - XE - 3 * (size_t)WS2; }
    float4 v = *(const float4*)(src + off);
    bf16x4 o; o[0] = f2bf(v.x); o[1] = f2bf(v.y); o[2] = f2bf(v.z); o[3] = f2bf(v.w);
    *(bf16x4*)(dst + off) = o;
}

// ---------------------------------------------------------------------------
// bf16 MFMA GEMM: Y[M,N] = A[M,K] @ W[N,K]^T (+bias).
// QSCALE: multiply the first C output columns (the Q block of fused QKV) by
// SOFT_SCALE so attn's exp2 needs no per-element multiply.
// ---------------------------------------------------------------------------
constexpr int BM = 128;

template<int BN_, int WMW, int WNW, int OUT_BF16, int QSCALE>
__global__ __launch_bounds__(256)
void gemm_bt(const short* __restrict__ A, const short* __restrict__ W,
             const float* __restrict__ bias0, const float* __restrict__ bias1,
             const float* __restrict__ bias2,
             void* __restrict__ Yv, int Ndim, int Kdim) {
    constexpr int MT  = BM / WMW / 16;
    constexpr int NT  = BN_ / WNW / 16;
    constexpr int NCH = (BM + BN_) / 16;     // 16-row chunks per k-half

    __shared__ short As[2][BM * 32];
    __shared__ short Bs[2][BN_ * 32];

    const int tid  = threadIdx.x;
    const int wave = tid >> 6;
    const int lane = tid & 63;
    const int li   = lane & 15;
    const int quad = lane >> 4;
    const int wm   = wave % WMW;
    const int wn   = wave / WMW;
    const int m0   = blockIdx.y * BM;
    const int n0   = blockIdx.x * BN_;

    f32x4 acc[MT][NT];
    #pragma unroll
    for (int i = 0; i < MT; ++i)
        #pragma unroll
        for (int j = 0; j < NT; ++j)
            acc[i][j] = (f32x4){0.f, 0.f, 0.f, 0.f};

    const int lrow = lane >> 2;          // 0..15 row within 16-row chunk
    const int lkof = (lane & 3) * 8;     // 16B chunk within 32-short half-row

    for (int k0 = 0; k0 < Kdim; k0 += 64) {
        __syncthreads();
        #pragma unroll
        for (int h = 0; h < 2; ++h)
            #pragma unroll
            for (int ii = 0; ii < NCH / 4; ++ii) {
                int c = ii * 4 + wave;
                if (c < BM / 16)
                    async_copy16(A + (size_t)(m0 + c * 16 + lrow) * Kdim
                                   + k0 + h * 32 + lkof,
                                 &As[h][c * 512]);
                else
                    async_copy16(W + (size_t)(n0 + (c - BM / 16) * 16 + lrow) * Kdim
                                   + k0 + h * 32 + lkof,
                                 &Bs[h][(c - BM / 16) * 512]);
            }
        __syncthreads();

        #pragma unroll
        for (int h = 0; h < 2; ++h) {
            bf16x8 af[MT], bfr[NT];
            #pragma unroll
            for (int t = 0; t < MT; ++t)
                af[t] = *(const bf16x8*)&As[h][(wm * MT * 16 + t * 16 + li) * 32 + quad * 8];
            #pragma unroll
            for (int t = 0; t < NT; ++t)
                bfr[t] = *(const bf16x8*)&Bs[h][(wn * NT * 16 + t * 16 + li) * 32 + quad * 8];
            #pragma unroll
            for (int i = 0; i < MT; ++i)
                #pragma unroll
                for (int j = 0; j < NT; ++j)
                    acc[i][j] = __builtin_amdgcn_mfma_f32_16x16x32_bf16(
                        af[i], bfr[j], acc[i][j], 0, 0, 0);
        }
    }

    float bb[NT];
    #pragma unroll
    for (int nt = 0; nt < NT; ++nt) bb[nt] = 0.f;
    if (bias0) {
        int s = n0 / C;
        const float* bp = (s == 0) ? bias0 : ((s == 1) ? bias1 : bias2);
        int nb = n0 % C;
        #pragma unroll
        for (int nt = 0; nt < NT; ++nt)
            bb[nt] = bp[nb + wn * NT * 16 + nt * 16 + li];
    }

    #pragma unroll
    for (int mt = 0; mt < MT; ++mt)
        #pragma unroll
        for (int nt = 0; nt < NT; ++nt)
            #pragma unroll
            for (int r = 0; r < 4; ++r) {
                int row = m0 + wm * MT * 16 + mt * 16 + quad * 4 + r;
                int col = n0 + wn * NT * 16 + nt * 16 + li;
                float v = acc[mt][nt][r] + bb[nt];
                if constexpr (QSCALE) {
                    if (n0 < C) v *= SOFT_SCALE;   // wave-uniform branch
                }
                if constexpr (OUT_BF16)
                    ((short*)Yv)[(size_t)row * Ndim + col] = f2bf(v);
                else
                    ((float*)Yv)[(size_t)row * Ndim + col] = v;
            }
}

// ---------------------------------------------------------------------------
// MFMA flash attention, 32x32x16, in-register softmax, 2-way SPLIT-K
// (in-block, round-2 verified-correct structure).
//
// 512 threads = 8 waves: wave w -> q-subtile (w&3, 32 rows), k-half (w>>2).
// Valid because this softmax has NO running max: oacc/lacc are pure sums
// over k, so the two k-halves just add at the end (LDS reduction).
//
// __launch_bounds__(512, 4): round 2 used (512, 6) which capped the
// allocator at ~85 regs < ~112 live (48 acc + 16 qf + 16 prefetch + temps)
// -> catastrophic scratch spill (VGPR_Count 40, WRITE_SIZE 1.5 GB, 593 us).
// (512, 4) allows 128 regs/wave: no spill, 4 waves/SIMD = 16 waves/CU
// (2 blocks/CU x 8 waves; LDS 2 x 50 KB <= 160 KB) vs baseline 12.
// ---------------------------------------------------------------------------
constexpr int QT   = 128;
constexpr int KTT  = 64;
constexpr int LSTR = 72;
constexpr int QS   = NQKV;
constexpr int KHT  = T / 2;        // 1024 k-tokens per k-half

__global__ __launch_bounds__(512, 4)
void attn_fwd(const short* __restrict__ QKV, short* __restrict__ O) {
    __shared__ short smem[25088];   // 50176 B: staging (36864) U reduction

    const int tid  = threadIdx.x;
    const int wave = tid >> 6;          // 0..7
    const int lane = tid & 63;
    const int r31  = lane & 31;
    const int hi   = lane >> 5;
    const int qs   = wave & 3;          // q sub-tile within block
    const int kh   = wave >> 2;         // k half (compute role)
    const int strm = tid >> 8;          // k-stream (staging role)
    const int t8   = tid & 255;
    const int b    = blockIdx.z;
    const int h    = blockIdx.y;
    const int qrow = blockIdx.x * QT + qs * 32;

    short* KsS = smem + strm * 4608;            // staging: K tile 64 x 72
    short* VtS = smem + 9216 + strm * 4608;     // staging: V^T tile 64 x 72
    const short* KsC = smem + kh * 4608;        // compute
    const short* VtC = smem + 9216 + kh * 4608;

    const short* Qg = QKV + (size_t)(b * T) * QS + h * Dh;
    const short* Kg = QKV + (size_t)(b * T) * QS + C + h * Dh;
    const short* Vg = QKV + (size_t)(b * T) * QS + 2 * C + h * Dh;

    // Q B-fragments: lane holds Q[qrow + (lane&31)][k = f*16 + hi*8 .. +7]
    bf16x8 qf[4];
    #pragma unroll
    for (int f = 0; f < 4; ++f)
        qf[f] = *(const bf16x8*)(Qg + (size_t)(qrow + r31) * QS + f * 16 + hi * 8);

    bf16x8 ones;
    #pragma unroll
    for (int i = 0; i < 8; ++i) ones[i] = (short)0x3F80;

    f32x16 oacc0 = (f32x16)(0.f);
    f32x16 oacc1 = (f32x16)(0.f);
    f32x16 lacc  = (f32x16)(0.f);

    // staging thread roles within the 256-thread stream group
    const int ktok = t8 >> 3;          // 0..31
    const int kch  = t8 & 7;
    const int vd2  = (t8 & 31) * 2;
    const int vg   = t8 >> 5;          // 0..7
    const int tbS  = strm * KHT;       // staging token base

    int4 kpre[2];
    unsigned vpre[8];
    kpre[0] = *(const int4*)(Kg + (size_t)(tbS + ktok)      * QS + kch * 8);
    kpre[1] = *(const int4*)(Kg + (size_t)(tbS + ktok + 32) * QS + kch * 8);
    #pragma unroll
    for (int t2 = 0; t2 < 8; ++t2)
        vpre[t2] = *(const unsigned*)(Vg + (size_t)(tbS + vg * 8 + t2) * QS + vd2);

    for (int ktl = 0; ktl < KHT; ktl += KTT) {
        __syncthreads();

        *(int4*)&KsS[ktok * LSTR + kch * 8]        = kpre[0];
        *(int4*)&KsS[(ktok + 32) * LSTR + kch * 8] = kpre[1];
        {
            unsigned lo[4], hh[4];
            #pragma unroll
            for (int j = 0; j < 4; ++j) {
                lo[j] = __builtin_amdgcn_perm(vpre[2 * j + 1], vpre[2 * j], 0x05040100u);
                hh[j] = __builtin_amdgcn_perm(vpre[2 * j + 1], vpre[2 * j], 0x07060302u);
            }
            *(int4*)&VtS[vd2 * LSTR + vg * 8]       = make_int4(lo[0], lo[1], lo[2], lo[3]);
            *(int4*)&VtS[(vd2 + 1) * LSTR + vg * 8] = make_int4(hh[0], hh[1], hh[2], hh[3]);
        }
        __syncthreads();

        if (ktl + KTT < KHT) {
            const size_t nb = tbS + ktl + KTT;
            kpre[0] = *(const int4*)(Kg + (nb + ktok)      * QS + kch * 8);
            kpre[1] = *(const int4*)(Kg + (nb + ktok + 32) * QS + kch * 8);
            #pragma unroll
            for (int t2 = 0; t2 < 8; ++t2)
                vpre[t2] = *(const unsigned*)(Vg + (nb + vg * 8 + t2) * QS + vd2);
        }

        // ---- QK^T: S[k][q] for this wave's 64-token tile ----
        f32x16 st0 = (f32x16)(0.f);
        f32x16 st1 = (f32x16)(0.f);
        __builtin_amdgcn_s_setprio(1);
        #pragma unroll
        for (int f = 0; f < 4; ++f) {
            bf16x8 k0 = *(const bf16x8*)&KsC[(r31)      * LSTR + f * 16 + hi * 8];
            bf16x8 k1 = *(const bf16x8*)&KsC[(32 + r31) * LSTR + f * 16 + hi * 8];
            st0 = __builtin_amdgcn_mfma_f32_32x32x16_bf16(k0, qf[f], st0, 0, 0, 0);
            st1 = __builtin_amdgcn_mfma_f32_32x32x16_bf16(k1, qf[f], st1, 0, 0, 0);
        }
        __builtin_amdgcn_s_setprio(0);

        // ---- per 32-token k-block: exp2 -> bf16 frags (in reg) -> PV ----
        #pragma unroll
        for (int kb = 0; kb < 2; ++kb) {
            f32x16 s = kb ? st1 : st0;          // kb is unroll-constant
            unsigned d[8];
            #pragma unroll
            for (int j = 0; j < 8; ++j) {
                float pa = __builtin_amdgcn_exp2f(s[2 * j]);
                float pb = __builtin_amdgcn_exp2f(s[2 * j + 1]);
                d[j] = pk_bf16(pa, pb);
            }
            // redistribute across lane^32 partners
            auto s02 = __builtin_amdgcn_permlane32_swap(d[0], d[2], false, false);
            auto s13 = __builtin_amdgcn_permlane32_swap(d[1], d[3], false, false);
            auto s46 = __builtin_amdgcn_permlane32_swap(d[4], d[6], false, false);
            auto s57 = __builtin_amdgcn_permlane32_swap(d[5], d[7], false, false);
            bf16x8 pf0 = mk8(s02[0], s13[0], s02[1], s13[1]);  // k = kb*32 + 0..15
            bf16x8 pf1 = mk8(s46[0], s57[0], s46[1], s57[1]);  // k = kb*32 + 16..31

            __builtin_amdgcn_s_setprio(1);
            lacc = __builtin_amdgcn_mfma_f32_32x32x16_bf16(pf0, ones, lacc, 0, 0, 0);
            lacc = __builtin_amdgcn_mfma_f32_32x32x16_bf16(pf1, ones, lacc, 0, 0, 0);

            bf16x8 v00 = *(const bf16x8*)&VtC[(r31)      * LSTR + kb * 32 + hi * 8];
            bf16x8 v01 = *(const bf16x8*)&VtC[(r31)      * LSTR + kb * 32 + 16 + hi * 8];
            bf16x8 v10 = *(const bf16x8*)&VtC[(32 + r31) * LSTR + kb * 32 + hi * 8];
            bf16x8 v11 = *(const bf16x8*)&VtC[(32 + r31) * LSTR + kb * 32 + 16 + hi * 8];
            oacc0 = __builtin_amdgcn_mfma_f32_32x32x16_bf16(pf0, v00, oacc0, 0, 0, 0);
            oacc0 = __builtin_amdgcn_mfma_f32_32x32x16_bf16(pf1, v01, oacc0, 0, 0, 0);
            oacc1 = __builtin_amdgcn_mfma_f32_32x32x16_bf16(pf0, v10, oacc1, 0, 0, 0);
            oacc1 = __builtin_amdgcn_mfma_f32_32x32x16_bf16(pf1, v11, oacc1, 0, 0, 0);
            __builtin_amdgcn_s_setprio(0);
        }
    }

    // ---- split-K combine: k-half 1 dumps partials to LDS, half 0 adds ----
    __syncthreads();                    // all K/V LDS reads done
    float* red = (float*)smem;
    if (kh == 1) {
        int base = ((wave - 4) * 64 + lane) * 49;   // stride 49: conflict-free
        #pragma unroll
        for (int r = 0; r < 16; ++r) {
            red[base + r]      = oacc0[r];
            red[base + 16 + r] = oacc1[r];
            red[base + 32 + r] = lacc[r];
        }
    }
    __syncthreads();
    if (kh == 0) {
        int base = (wave * 64 + lane) * 49;
        #pragma unroll
        for (int r = 0; r < 16; ++r) {
            float o0 = oacc0[r] + red[base + r];
            float o1 = oacc1[r] + red[base + 16 + r];
            float l  = lacc[r]  + red[base + 32 + r];
            float inv = 1.0f / l;
            int row = (r & 3) + 8 * (r >> 2) + 4 * hi;
            short* op = O + (size_t)(b * T + qrow + row) * C + h * Dh + r31;
            op[0]  = f2bf(o0 * inv);
            op[32] = f2bf(o1 * inv);
        }
    }
}

// ---------------------------------------------------------------------------
// Launch
// ---------------------------------------------------------------------------
extern "C" void kernel_launch(void* const* d_in, const int* in_sizes, int n_in,
                              void* d_out, int out_size, void* d_ws, size_t ws_size,
                              hipStream_t stream) {
    (void)in_sizes; (void)n_in; (void)out_size; (void)ws_size;

    const float* x  = (const float*)d_in[0];
    const float* Wq = (const float*)d_in[1];
    const float* bq = (const float*)d_in[2];
    const float* Wk = (const float*)d_in[3];
    const float* bk = (const float*)d_in[4];
    const float* Wv = (const float*)d_in[5];
    const float* bv = (const float*)d_in[6];
    const float* Wp = (const float*)d_in[7];
    float* out = (float*)d_out;

    short* xb    = (short*)d_ws;                 // [M][C]      bf16
    short* Wqkv  = xb + (size_t)M * C;           // [2304][768] bf16
    short* Wpb   = Wqkv + 3 * (size_t)WS2;       // [768][768]  bf16
    short* QKVb  = Wpb + (size_t)WS2;            // [M][2304]   bf16 (Q pre-scaled)
    short* AOb   = QKVb + (size_t)M * NQKV;      // [M][C]      bf16

    convert_all<<<dim3(CV_TOTAL / 1024), 256, 0, stream>>>(
        x, Wq, Wk, Wv, Wp, xb, Wqkv, Wpb);

    // Fused QKV projection: [8192 x 2304], Q columns scaled by SOFT_SCALE
    gemm_bt<128, 2, 2, 1, 1><<<dim3(NQKV / 128, M / BM), 256, 0, stream>>>(
        xb, Wqkv, bq, bk, bv, QKVb, NQKV, C);

    attn_fwd<<<dim3(T / QT, H, B), 512, 0, stream>>>(QKVb, AOb);

    // Output projection: [8192 x 768] fp32 out
    gemm_bt<64, 4, 1, 0, 0><<<dim3(C / 64, M / BM), 256, 0, stream>>>(
        AOb, Wpb, nullptr, nullptr, nullptr, out, C, C);
}

// Round 5
// 244.233 us; speedup vs baseline: 3.0749x; 1.0028x over previous
//
#include <hip/hip_runtime.h>
#include <hip/hip_bf16.h>
#include <cmath>

// Problem constants
constexpr int B  = 4;
constexpr int T  = 2048;
constexpr int C  = 768;
constexpr int H  = 12;
constexpr int Dh = 64;
constexpr int M  = B * T;          // 8192
constexpr int NQKV = 3 * C;        // 2304 fused QKV output width
constexpr int WS2  = C * C;        // 589824 elems per weight matrix

typedef short bf16x8 __attribute__((ext_vector_type(8)));
typedef short bf16x4 __attribute__((ext_vector_type(4)));
typedef float f32x4  __attribute__((ext_vector_type(4)));
typedef float f32x16 __attribute__((ext_vector_type(16)));

// softmax scale folded into Q at GEMM epilogue: (1/sqrt(Dh)) * log2(e)
constexpr float SOFT_SCALE = 0.18033688011112042f;

__device__ inline short f2bf(float f) {   // fp32 -> bf16 round-nearest-even
    unsigned u = __float_as_uint(f);
    u += 0x7fffu + ((u >> 16) & 1u);
    return (short)(u >> 16);
}

__device__ inline unsigned pk_bf16(float a, float b) {  // packed pair (RNE)
    __hip_bfloat162 h = __float22bfloat162_rn(float2{a, b});
    return *(unsigned*)&h;
}

__device__ inline bf16x8 mk8(unsigned a, unsigned b, unsigned c, unsigned d) {
    union { unsigned u[4]; bf16x8 v; } x;
    x.u[0] = a; x.u[1] = b; x.u[2] = c; x.u[3] = d;
    return x.v;
}

// global(AS1) -> LDS(AS3) 16-byte async copy; HW writes ldsbase + lane*16.
typedef const __attribute__((address_space(1))) unsigned GU;
typedef __attribute__((address_space(3))) unsigned LU;
__device__ inline void async_copy16(const void* g, void* l) {
    __builtin_amdgcn_global_load_lds((GU*)g, (LU*)l, 16, 0, 0);
}

// ---------------------------------------------------------------------------
// Fused fp32 -> bf16 convert for x + all four weights (one launch).
// ---------------------------------------------------------------------------
constexpr size_t XE = (size_t)M * C;                // 6291456
constexpr size_t CV_TOTAL = XE + 4 * (size_t)WS2;   // 8650752

__global__ __launch_bounds__(256)
void convert_all(const float* __restrict__ x,  const float* __restrict__ Wq,
                 const float* __restrict__ Wk, const float* __restrict__ Wv,
                 const float* __restrict__ Wp,
                 short* __restrict__ xb, short* __restrict__ Wqkv,
                 short* __restrict__ Wpb) {
    size_t i = ((size_t)blockIdx.x * 256 + threadIdx.x) * 4;
    const float* src; short* dst; size_t off;
    if (i < XE)                        { src = x;  dst = xb;            off = i; }
    else if (i < XE + WS2)             { src = Wq; dst = Wqkv;          off = i - XE; }
    else if (i < XE + 2 * (size_t)WS2) { src = Wk; dst = Wqkv + WS2;    off = i - XE - WS2; }
    else if (i < XE + 3 * (size_t)WS2) { src = Wv; dst = Wqkv + 2 * WS2; off = i - XE - 2 * (size_t)WS2; }
    else                               { src = Wp; dst = Wpb;           off = i - XE - 3 * (size_t)WS2; }
    float4 v = *(const float4*)(src + off);
    bf16x4 o; o[0] = f2bf(v.x); o[1] = f2bf(v.y); o[2] = f2bf(v.z); o[3] = f2bf(v.w);
    *(bf16x4*)(dst + off) = o;
}

// ---------------------------------------------------------------------------
// bf16 MFMA GEMM: Y[M,N] = A[M,K] @ W[N,K]^T (+bias).
// QSCALE: multiply the first C output columns (the Q block of fused QKV) by
// SOFT_SCALE so attn's exp2 needs no per-element multiply.
// ---------------------------------------------------------------------------
constexpr int BM = 128;

template<int BN_, int WMW, int WNW, int OUT_BF16, int QSCALE>
__global__ __launch_bounds__(256)
void gemm_bt(const short* __restrict__ A, const short* __restrict__ W,
             const float* __restrict__ bias0, const float* __restrict__ bias1,
             const float* __restrict__ bias2,
             void* __restrict__ Yv, int Ndim, int Kdim) {
    constexpr int MT  = BM / WMW / 16;
    constexpr int NT  = BN_ / WNW / 16;
    constexpr int NCH = (BM + BN_) / 16;     // 16-row chunks per k-half

    __shared__ short As[2][BM * 32];
    __shared__ short Bs[2][BN_ * 32];

    const int tid  = threadIdx.x;
    const int wave = tid >> 6;
    const int lane = tid & 63;
    const int li   = lane & 15;
    const int quad = lane >> 4;
    const int wm   = wave % WMW;
    const int wn   = wave / WMW;
    const int m0   = blockIdx.y * BM;
    const int n0   = blockIdx.x * BN_;

    f32x4 acc[MT][NT];
    #pragma unroll
    for (int i = 0; i < MT; ++i)
        #pragma unroll
        for (int j = 0; j < NT; ++j)
            acc[i][j] = (f32x4){0.f, 0.f, 0.f, 0.f};

    const int lrow = lane >> 2;          // 0..15 row within 16-row chunk
    const int lkof = (lane & 3) * 8;     // 16B chunk within 32-short half-row

    for (int k0 = 0; k0 < Kdim; k0 += 64) {
        __syncthreads();
        #pragma unroll
        for (int h = 0; h < 2; ++h)
            #pragma unroll
            for (int ii = 0; ii < NCH / 4; ++ii) {
                int c = ii * 4 + wave;
                if (c < BM / 16)
                    async_copy16(A + (size_t)(m0 + c * 16 + lrow) * Kdim
                                   + k0 + h * 32 + lkof,
                                 &As[h][c * 512]);
                else
                    async_copy16(W + (size_t)(n0 + (c - BM / 16) * 16 + lrow) * Kdim
                                   + k0 + h * 32 + lkof,
                                 &Bs[h][(c - BM / 16) * 512]);
            }
        __syncthreads();

        #pragma unroll
        for (int h = 0; h < 2; ++h) {
            bf16x8 af[MT], bfr[NT];
            #pragma unroll
            for (int t = 0; t < MT; ++t)
                af[t] = *(const bf16x8*)&As[h][(wm * MT * 16 + t * 16 + li) * 32 + quad * 8];
            #pragma unroll
            for (int t = 0; t < NT; ++t)
                bfr[t] = *(const bf16x8*)&Bs[h][(wn * NT * 16 + t * 16 + li) * 32 + quad * 8];
            #pragma unroll
            for (int i = 0; i < MT; ++i)
                #pragma unroll
                for (int j = 0; j < NT; ++j)
                    acc[i][j] = __builtin_amdgcn_mfma_f32_16x16x32_bf16(
                        af[i], bfr[j], acc[i][j], 0, 0, 0);
        }
    }

    float bb[NT];
    #pragma unroll
    for (int nt = 0; nt < NT; ++nt) bb[nt] = 0.f;
    if (bias0) {
        int s = n0 / C;
        const float* bp = (s == 0) ? bias0 : ((s == 1) ? bias1 : bias2);
        int nb = n0 % C;
        #pragma unroll
        for (int nt = 0; nt < NT; ++nt)
            bb[nt] = bp[nb + wn * NT * 16 + nt * 16 + li];
    }

    #pragma unroll
    for (int mt = 0; mt < MT; ++mt)
        #pragma unroll
        for (int nt = 0; nt < NT; ++nt)
            #pragma unroll
            for (int r = 0; r < 4; ++r) {
                int row = m0 + wm * MT * 16 + mt * 16 + quad * 4 + r;
                int col = n0 + wn * NT * 16 + nt * 16 + li;
                float v = acc[mt][nt][r] + bb[nt];
                if constexpr (QSCALE) {
                    if (n0 < C) v *= SOFT_SCALE;   // wave-uniform branch
                }
                if constexpr (OUT_BF16)
                    ((short*)Yv)[(size_t)row * Ndim + col] = f2bf(v);
                else
                    ((float*)Yv)[(size_t)row * Ndim + col] = v;
            }
}

// ---------------------------------------------------------------------------
// MFMA flash attention, 32x32x16, in-register softmax (round-1 verified
// body), with 128-token K/V macro-tiles: TWO 64-token tiles staged per
// barrier pair -> barrier count halved (64 -> 32 per block), compute window
// per barrier doubled (better latency hiding for prefetch + dep chains).
//
// r4 evidence: occupancy 27->35% gave NO speedup (barrier-locked serial
// chain is the bound, not wave count) -> amortize the barriers instead.
// Two separate [64][72] LDS buffer pairs preserve r1's verified stride-72
// bank behavior exactly; compute body per half is byte-identical to r1.
// Live regs ~ r1 + 16 prefetch ~ 160 < 170 (launch_bounds 256,3 budget).
// ---------------------------------------------------------------------------
constexpr int QT   = 128;
constexpr int KTT  = 64;
constexpr int LSTR = 72;
constexpr int QS   = NQKV;

__global__ __launch_bounds__(256, 3)
void attn_fwd(const short* __restrict__ QKV, short* __restrict__ O) {
    __shared__ short Ks[2][KTT * LSTR];
    __shared__ short Vt[2][Dh * LSTR];

    const int tid  = threadIdx.x;
    const int wave = tid >> 6;
    const int lane = tid & 63;
    const int r31  = lane & 31;
    const int hi   = lane >> 5;
    const int b    = blockIdx.z;
    const int h    = blockIdx.y;
    const int qw   = blockIdx.x * QT + wave * 32;

    const short* Qg = QKV + (size_t)(b * T) * QS + h * Dh;
    const short* Kg = QKV + (size_t)(b * T) * QS + C + h * Dh;
    const short* Vg = QKV + (size_t)(b * T) * QS + 2 * C + h * Dh;

    // Q B-fragments: lane holds Q[qw + (lane&31)][k = f*16 + hi*8 .. +7]
    bf16x8 qf[4];
    #pragma unroll
    for (int f = 0; f < 4; ++f)
        qf[f] = *(const bf16x8*)(Qg + (size_t)(qw + r31) * QS + f * 16 + hi * 8);

    bf16x8 ones;
    #pragma unroll
    for (int i = 0; i < 8; ++i) ones[i] = (short)0x3F80;

    f32x16 oacc0 = (f32x16)(0.f);
    f32x16 oacc1 = (f32x16)(0.f);
    f32x16 lacc  = (f32x16)(0.f);

    const int ktok = tid >> 3;
    const int kch  = tid & 7;
    const int vd2  = (tid & 31) * 2;
    const int vg   = tid >> 5;

    int4 kpre[2][2];
    unsigned vpre[2][8];
    #pragma unroll
    for (int hf = 0; hf < 2; ++hf) {
        const size_t tb = hf * KTT;
        kpre[hf][0] = *(const int4*)(Kg + (tb + ktok)      * QS + kch * 8);
        kpre[hf][1] = *(const int4*)(Kg + (tb + ktok + 32) * QS + kch * 8);
        #pragma unroll
        for (int t2 = 0; t2 < 8; ++t2)
            vpre[hf][t2] = *(const unsigned*)(Vg + (tb + vg * 8 + t2) * QS + vd2);
    }

    for (int kt = 0; kt < T; kt += 2 * KTT) {
        __syncthreads();

        #pragma unroll
        for (int hf = 0; hf < 2; ++hf) {
            *(int4*)&Ks[hf][ktok * LSTR + kch * 8]        = kpre[hf][0];
            *(int4*)&Ks[hf][(ktok + 32) * LSTR + kch * 8] = kpre[hf][1];
            unsigned lo[4], hh[4];
            #pragma unroll
            for (int j = 0; j < 4; ++j) {
                lo[j] = __builtin_amdgcn_perm(vpre[hf][2 * j + 1], vpre[hf][2 * j], 0x05040100u);
                hh[j] = __builtin_amdgcn_perm(vpre[hf][2 * j + 1], vpre[hf][2 * j], 0x07060302u);
            }
            *(int4*)&Vt[hf][vd2 * LSTR + vg * 8]       = make_int4(lo[0], lo[1], lo[2], lo[3]);
            *(int4*)&Vt[hf][(vd2 + 1) * LSTR + vg * 8] = make_int4(hh[0], hh[1], hh[2], hh[3]);
        }
        __syncthreads();

        if (kt + 2 * KTT < T) {
            #pragma unroll
            for (int hf = 0; hf < 2; ++hf) {
                const size_t nb = kt + 2 * KTT + hf * KTT;
                kpre[hf][0] = *(const int4*)(Kg + (nb + ktok)      * QS + kch * 8);
                kpre[hf][1] = *(const int4*)(Kg + (nb + ktok + 32) * QS + kch * 8);
                #pragma unroll
                for (int t2 = 0; t2 < 8; ++t2)
                    vpre[hf][t2] = *(const unsigned*)(Vg + (nb + vg * 8 + t2) * QS + vd2);
            }
        }

        #pragma unroll
        for (int half = 0; half < 2; ++half) {
            // ---- QK^T: S[k][q] for this 64-token tile, two 32-row blocks ----
            f32x16 st0 = (f32x16)(0.f);
            f32x16 st1 = (f32x16)(0.f);
            __builtin_amdgcn_s_setprio(1);
            #pragma unroll
            for (int f = 0; f < 4; ++f) {
                bf16x8 k0 = *(const bf16x8*)&Ks[half][(r31)      * LSTR + f * 16 + hi * 8];
                bf16x8 k1 = *(const bf16x8*)&Ks[half][(32 + r31) * LSTR + f * 16 + hi * 8];
                st0 = __builtin_amdgcn_mfma_f32_32x32x16_bf16(k0, qf[f], st0, 0, 0, 0);
                st1 = __builtin_amdgcn_mfma_f32_32x32x16_bf16(k1, qf[f], st1, 0, 0, 0);
            }
            __builtin_amdgcn_s_setprio(0);

            // ---- per 32-token k-block: exp2 -> bf16 frags (in reg) -> PV ----
            #pragma unroll
            for (int kb = 0; kb < 2; ++kb) {
                f32x16 s = kb ? st1 : st0;          // kb is unroll-constant
                unsigned d[8];
                #pragma unroll
                for (int j = 0; j < 8; ++j) {
                    float pa = __builtin_amdgcn_exp2f(s[2 * j]);
                    float pb = __builtin_amdgcn_exp2f(s[2 * j + 1]);
                    d[j] = pk_bf16(pa, pb);
                }
                // redistribute across lane^32 partners
                auto s02 = __builtin_amdgcn_permlane32_swap(d[0], d[2], false, false);
                auto s13 = __builtin_amdgcn_permlane32_swap(d[1], d[3], false, false);
                auto s46 = __builtin_amdgcn_permlane32_swap(d[4], d[6], false, false);
                auto s57 = __builtin_amdgcn_permlane32_swap(d[5], d[7], false, false);
                bf16x8 pf0 = mk8(s02[0], s13[0], s02[1], s13[1]);  // k = kb*32 + 0..15
                bf16x8 pf1 = mk8(s46[0], s57[0], s46[1], s57[1]);  // k = kb*32 + 16..31

                __builtin_amdgcn_s_setprio(1);
                lacc = __builtin_amdgcn_mfma_f32_32x32x16_bf16(pf0, ones, lacc, 0, 0, 0);
                lacc = __builtin_amdgcn_mfma_f32_32x32x16_bf16(pf1, ones, lacc, 0, 0, 0);

                bf16x8 v00 = *(const bf16x8*)&Vt[half][(r31)      * LSTR + kb * 32 + hi * 8];
                bf16x8 v01 = *(const bf16x8*)&Vt[half][(r31)      * LSTR + kb * 32 + 16 + hi * 8];
                bf16x8 v10 = *(const bf16x8*)&Vt[half][(32 + r31) * LSTR + kb * 32 + hi * 8];
                bf16x8 v11 = *(const bf16x8*)&Vt[half][(32 + r31) * LSTR + kb * 32 + 16 + hi * 8];
                oacc0 = __builtin_amdgcn_mfma_f32_32x32x16_bf16(pf0, v00, oacc0, 0, 0, 0);
                oacc0 = __builtin_amdgcn_mfma_f32_32x32x16_bf16(pf1, v01, oacc0, 0, 0, 0);
                oacc1 = __builtin_amdgcn_mfma_f32_32x32x16_bf16(pf0, v10, oacc1, 0, 0, 0);
                oacc1 = __builtin_amdgcn_mfma_f32_32x32x16_bf16(pf1, v11, oacc1, 0, 0, 0);
                __builtin_amdgcn_s_setprio(0);
            }
        }
    }

    // oacc: O[q][d], lane holds col d = dblk*32 + (lane&31),
    // reg r -> q-row (r&3) + 8*(r>>2) + 4*hi. lacc reg r -> l[same q].
    #pragma unroll
    for (int r = 0; r < 16; ++r) {
        float inv = 1.0f / lacc[r];
        int row = (r & 3) + 8 * (r >> 2) + 4 * hi;
        short* op = O + (size_t)(b * T + qw + row) * C + h * Dh + r31;
        op[0]  = f2bf(oacc0[r] * inv);
        op[32] = f2bf(oacc1[r] * inv);
    }
}

// ---------------------------------------------------------------------------
// Launch
// ---------------------------------------------------------------------------
extern "C" void kernel_launch(void* const* d_in, const int* in_sizes, int n_in,
                              void* d_out, int out_size, void* d_ws, size_t ws_size,
                              hipStream_t stream) {
    (void)in_sizes; (void)n_in; (void)out_size; (void)ws_size;

    const float* x  = (const float*)d_in[0];
    const float* Wq = (const float*)d_in[1];
    const float* bq = (const float*)d_in[2];
    const float* Wk = (const float*)d_in[3];
    const float* bk = (const float*)d_in[4];
    const float* Wv = (const float*)d_in[5];
    const float* bv = (const float*)d_in[6];
    const float* Wp = (const float*)d_in[7];
    float* out = (float*)d_out;

    short* xb    = (short*)d_ws;                 // [M][C]      bf16
    short* Wqkv  = xb + (size_t)M * C;           // [2304][768] bf16
    short* Wpb   = Wqkv + 3 * (size_t)WS2;       // [768][768]  bf16
    short* QKVb  = Wpb + (size_t)WS2;            // [M][2304]   bf16 (Q pre-scaled)
    short* AOb   = QKVb + (size_t)M * NQKV;      // [M][C]      bf16

    convert_all<<<dim3(CV_TOTAL / 1024), 256, 0, stream>>>(
        x, Wq, Wk, Wv, Wp, xb, Wqkv, Wpb);

    // Fused QKV projection: [8192 x 2304], Q columns scaled by SOFT_SCALE
    gemm_bt<128, 2, 2, 1, 1><<<dim3(NQKV / 128, M / BM), 256, 0, stream>>>(
        xb, Wqkv, bq, bk, bv, QKVb, NQKV, C);

    attn_fwd<<<dim3(T / QT, H, B), 256, 0, stream>>>(QKVb, AOb);

    // Output projection: [8192 x 768] fp32 out
    gemm_bt<64, 4, 1, 0, 0><<<dim3(C / 64, M / BM), 256, 0, stream>>>(
        AOb, Wpb, nullptr, nullptr, nullptr, out, C, C);
}

// Round 6
// 231.567 us; speedup vs baseline: 3.2431x; 1.0547x over previous
//
#include <hip/hip_runtime.h>
#include <hip/hip_bf16.h>
#include <cmath>

// Problem constants
constexpr int B  = 4;
constexpr int T  = 2048;
constexpr int C  = 768;
constexpr int H  = 12;
constexpr int Dh = 64;
constexpr int M  = B * T;          // 8192
constexpr int NQKV = 3 * C;        // 2304 fused QKV output width
constexpr int WS2  = C * C;        // 589824 elems per weight matrix

typedef short bf16x8 __attribute__((ext_vector_type(8)));
typedef short bf16x4 __attribute__((ext_vector_type(4)));
typedef float f32x4  __attribute__((ext_vector_type(4)));
typedef float f32x16 __attribute__((ext_vector_type(16)));

// softmax scale folded into Q at GEMM epilogue: (1/sqrt(Dh)) * log2(e)
constexpr float SOFT_SCALE = 0.18033688011112042f;

__device__ inline short f2bf(float f) {   // fp32 -> bf16 round-nearest-even
    unsigned u = __float_as_uint(f);
    u += 0x7fffu + ((u >> 16) & 1u);
    return (short)(u >> 16);
}

__device__ inline unsigned pk_bf16(float a, float b) {  // packed pair (RNE)
    __hip_bfloat162 h = __float22bfloat162_rn(float2{a, b});
    return *(unsigned*)&h;
}

__device__ inline bf16x8 mk8(unsigned a, unsigned b, unsigned c, unsigned d) {
    union { unsigned u[4]; bf16x8 v; } x;
    x.u[0] = a; x.u[1] = b; x.u[2] = c; x.u[3] = d;
    return x.v;
}

// global(AS1) -> LDS(AS3) 16-byte async copy; HW writes ldsbase + lane*16.
typedef const __attribute__((address_space(1))) unsigned GU;
typedef __attribute__((address_space(3))) unsigned LU;
__device__ inline void async_copy16(const void* g, void* l) {
    __builtin_amdgcn_global_load_lds((GU*)g, (LU*)l, 16, 0, 0);
}

// ---------------------------------------------------------------------------
// Fused fp32 -> bf16 convert for x + all four weights (one launch).
// ---------------------------------------------------------------------------
constexpr size_t XE = (size_t)M * C;                // 6291456
constexpr size_t CV_TOTAL = XE + 4 * (size_t)WS2;   // 8650752

__global__ __launch_bounds__(256)
void convert_all(const float* __restrict__ x,  const float* __restrict__ Wq,
                 const float* __restrict__ Wk, const float* __restrict__ Wv,
                 const float* __restrict__ Wp,
                 short* __restrict__ xb, short* __restrict__ Wqkv,
                 short* __restrict__ Wpb) {
    size_t i = ((size_t)blockIdx.x * 256 + threadIdx.x) * 4;
    const float* src; short* dst; size_t off;
    if (i < XE)                        { src = x;  dst = xb;            off = i; }
    else if (i < XE + WS2)             { src = Wq; dst = Wqkv;          off = i - XE; }
    else if (i < XE + 2 * (size_t)WS2) { src = Wk; dst = Wqkv + WS2;    off = i - XE - WS2; }
    else if (i < XE + 3 * (size_t)WS2) { src = Wv; dst = Wqkv + 2 * WS2; off = i - XE - 2 * (size_t)WS2; }
    else                               { src = Wp; dst = Wpb;           off = i - XE - 3 * (size_t)WS2; }
    float4 v = *(const float4*)(src + off);
    bf16x4 o; o[0] = f2bf(v.x); o[1] = f2bf(v.y); o[2] = f2bf(v.z); o[3] = f2bf(v.w);
    *(bf16x4*)(dst + off) = o;
}

// ---------------------------------------------------------------------------
// bf16 MFMA GEMM: Y[M,N] = A[M,K] @ W[N,K]^T (+bias).
// QSCALE: multiply the first C output columns (the Q block of fused QKV) by
// SOFT_SCALE so attn's exp2 needs no per-element multiply.
//
// XCD-slab swizzle (r6): 1-D grid, xcd = bid&7 (dispatch round-robin, m09).
// Each XCD owns a contiguous slab of 8 m-tiles (64 m-tiles / 8 XCDs) and
// iterates its n-tiles fastest. Per-XCD L2 working set drops from
// "all of A + all of W" (12-16 MB, pure L3 streaming) to A-slab + W
// (QKV: ~5 MB, proj: 2.75 MB <= 4 MB L2). Bijective: grid = 8*8*ntiles.
// ---------------------------------------------------------------------------
constexpr int BM = 128;
constexpr int MTILES = M / BM;       // 64

template<int BN_, int WMW, int WNW, int OUT_BF16, int QSCALE>
__global__ __launch_bounds__(256)
void gemm_bt(const short* __restrict__ A, const short* __restrict__ W,
             const float* __restrict__ bias0, const float* __restrict__ bias1,
             const float* __restrict__ bias2,
             void* __restrict__ Yv, int Ndim, int Kdim) {
    constexpr int MT  = BM / WMW / 16;
    constexpr int NT  = BN_ / WNW / 16;
    constexpr int NCH = (BM + BN_) / 16;     // 16-row chunks per k-half

    __shared__ short As[2][BM * 32];
    __shared__ short Bs[2][BN_ * 32];

    const int tid  = threadIdx.x;
    const int wave = tid >> 6;
    const int lane = tid & 63;
    const int li   = lane & 15;
    const int quad = lane >> 4;
    const int wm   = wave % WMW;
    const int wn   = wave / WMW;

    // XCD-slab block swizzle
    const int ntiles = Ndim / BN_;
    const int bid  = blockIdx.x;
    const int xcd  = bid & 7;
    const int idx  = bid >> 3;
    const int mloc = idx / ntiles;           // 0 .. MTILES/8-1
    const int ntt  = idx % ntiles;
    const int m0   = (xcd * (MTILES / 8) + mloc) * BM;
    const int n0   = ntt * BN_;

    f32x4 acc[MT][NT];
    #pragma unroll
    for (int i = 0; i < MT; ++i)
        #pragma unroll
        for (int j = 0; j < NT; ++j)
            acc[i][j] = (f32x4){0.f, 0.f, 0.f, 0.f};

    const int lrow = lane >> 2;          // 0..15 row within 16-row chunk
    const int lkof = (lane & 3) * 8;     // 16B chunk within 32-short half-row

    for (int k0 = 0; k0 < Kdim; k0 += 64) {
        __syncthreads();
        #pragma unroll
        for (int h = 0; h < 2; ++h)
            #pragma unroll
            for (int ii = 0; ii < NCH / 4; ++ii) {
                int c = ii * 4 + wave;
                if (c < BM / 16)
                    async_copy16(A + (size_t)(m0 + c * 16 + lrow) * Kdim
                                   + k0 + h * 32 + lkof,
                                 &As[h][c * 512]);
                else
                    async_copy16(W + (size_t)(n0 + (c - BM / 16) * 16 + lrow) * Kdim
                                   + k0 + h * 32 + lkof,
                                 &Bs[h][(c - BM / 16) * 512]);
            }
        __syncthreads();

        #pragma unroll
        for (int h = 0; h < 2; ++h) {
            bf16x8 af[MT], bfr[NT];
            #pragma unroll
            for (int t = 0; t < MT; ++t)
                af[t] = *(const bf16x8*)&As[h][(wm * MT * 16 + t * 16 + li) * 32 + quad * 8];
            #pragma unroll
            for (int t = 0; t < NT; ++t)
                bfr[t] = *(const bf16x8*)&Bs[h][(wn * NT * 16 + t * 16 + li) * 32 + quad * 8];
            #pragma unroll
            for (int i = 0; i < MT; ++i)
                #pragma unroll
                for (int j = 0; j < NT; ++j)
                    acc[i][j] = __builtin_amdgcn_mfma_f32_16x16x32_bf16(
                        af[i], bfr[j], acc[i][j], 0, 0, 0);
        }
    }

    float bb[NT];
    #pragma unroll
    for (int nt = 0; nt < NT; ++nt) bb[nt] = 0.f;
    if (bias0) {
        int s = n0 / C;
        const float* bp = (s == 0) ? bias0 : ((s == 1) ? bias1 : bias2);
        int nb = n0 % C;
        #pragma unroll
        for (int nt = 0; nt < NT; ++nt)
            bb[nt] = bp[nb + wn * NT * 16 + nt * 16 + li];
    }

    #pragma unroll
    for (int mt = 0; mt < MT; ++mt)
        #pragma unroll
        for (int nt = 0; nt < NT; ++nt)
            #pragma unroll
            for (int r = 0; r < 4; ++r) {
                int row = m0 + wm * MT * 16 + mt * 16 + quad * 4 + r;
                int col = n0 + wn * NT * 16 + nt * 16 + li;
                float v = acc[mt][nt][r] + bb[nt];
                if constexpr (QSCALE) {
                    if (n0 < C) v *= SOFT_SCALE;   // wave-uniform branch
                }
                if constexpr (OUT_BF16)
                    ((short*)Yv)[(size_t)row * Ndim + col] = f2bf(v);
                else
                    ((float*)Yv)[(size_t)row * Ndim + col] = v;
            }
}

// ---------------------------------------------------------------------------
// MFMA flash attention, 32x32x16 shape, in-register softmax (T12).
// EXACT round-1 verified kernel (95.4 us): r4 (split-K occupancy) and r5
// (barrier amortization) both failed to beat it — r4 proved wave count is
// not the bound, r5 spilled (WRITE_SIZE 157 MB). This structure's plateau.
// ---------------------------------------------------------------------------
constexpr int QT   = 128;
constexpr int KTT  = 64;
constexpr int LSTR = 72;
constexpr int QS   = NQKV;

__global__ __launch_bounds__(256, 3)
void attn_fwd(const short* __restrict__ QKV, short* __restrict__ O) {
    __shared__ short Ks[KTT * LSTR];
    __shared__ short Vt[Dh * LSTR];

    const int tid  = threadIdx.x;
    const int wave = tid >> 6;
    const int lane = tid & 63;
    const int r31  = lane & 31;
    const int hi   = lane >> 5;
    const int b    = blockIdx.z;
    const int h    = blockIdx.y;
    const int qw   = blockIdx.x * QT + wave * 32;

    const short* Qg = QKV + (size_t)(b * T) * QS + h * Dh;
    const short* Kg = QKV + (size_t)(b * T) * QS + C + h * Dh;
    const short* Vg = QKV + (size_t)(b * T) * QS + 2 * C + h * Dh;

    // Q B-fragments: lane holds Q[row = qw + (lane&31)][k = f*16 + hi*8 .. +7]
    bf16x8 qf[4];
    #pragma unroll
    for (int f = 0; f < 4; ++f)
        qf[f] = *(const bf16x8*)(Qg + (size_t)(qw + r31) * QS + f * 16 + hi * 8);

    bf16x8 ones;
    #pragma unroll
    for (int i = 0; i < 8; ++i) ones[i] = (short)0x3F80;

    f32x16 oacc0 = (f32x16)(0.f);
    f32x16 oacc1 = (f32x16)(0.f);
    f32x16 lacc  = (f32x16)(0.f);

    const int ktok = tid >> 3;
    const int kch  = tid & 7;
    const int vd2  = (tid & 31) * 2;
    const int vg   = tid >> 5;

    int4 kpre[2];
    unsigned vpre[8];
    kpre[0] = *(const int4*)(Kg + (size_t)(ktok)      * QS + kch * 8);
    kpre[1] = *(const int4*)(Kg + (size_t)(ktok + 32) * QS + kch * 8);
    #pragma unroll
    for (int t2 = 0; t2 < 8; ++t2)
        vpre[t2] = *(const unsigned*)(Vg + (size_t)(vg * 8 + t2) * QS + vd2);

    for (int kt = 0; kt < T; kt += KTT) {
        __syncthreads();

        *(int4*)&Ks[ktok * LSTR + kch * 8]        = kpre[0];
        *(int4*)&Ks[(ktok + 32) * LSTR + kch * 8] = kpre[1];
        {
            unsigned lo[4], hh[4];
            #pragma unroll
            for (int j = 0; j < 4; ++j) {
                lo[j] = __builtin_amdgcn_perm(vpre[2 * j + 1], vpre[2 * j], 0x05040100u);
                hh[j] = __builtin_amdgcn_perm(vpre[2 * j + 1], vpre[2 * j], 0x07060302u);
            }
            *(int4*)&Vt[vd2 * LSTR + vg * 8]       = make_int4(lo[0], lo[1], lo[2], lo[3]);
            *(int4*)&Vt[(vd2 + 1) * LSTR + vg * 8] = make_int4(hh[0], hh[1], hh[2], hh[3]);
        }
        __syncthreads();

        if (kt + KTT < T) {
            const size_t nb = kt + KTT;
            kpre[0] = *(const int4*)(Kg + (nb + ktok)      * QS + kch * 8);
            kpre[1] = *(const int4*)(Kg + (nb + ktok + 32) * QS + kch * 8);
            #pragma unroll
            for (int t2 = 0; t2 < 8; ++t2)
                vpre[t2] = *(const unsigned*)(Vg + (nb + vg * 8 + t2) * QS + vd2);
        }

        // ---- QK^T: S[k][q] for the 64-token tile, two 32-row k-blocks ----
        f32x16 st0 = (f32x16)(0.f);
        f32x16 st1 = (f32x16)(0.f);
        __builtin_amdgcn_s_setprio(1);
        #pragma unroll
        for (int f = 0; f < 4; ++f) {
            bf16x8 k0 = *(const bf16x8*)&Ks[(r31)      * LSTR + f * 16 + hi * 8];
            bf16x8 k1 = *(const bf16x8*)&Ks[(32 + r31) * LSTR + f * 16 + hi * 8];
            st0 = __builtin_amdgcn_mfma_f32_32x32x16_bf16(k0, qf[f], st0, 0, 0, 0);
            st1 = __builtin_amdgcn_mfma_f32_32x32x16_bf16(k1, qf[f], st1, 0, 0, 0);
        }
        __builtin_amdgcn_s_setprio(0);

        // ---- per 32-token k-block: exp2 -> bf16 frags (in reg) -> PV ----
        #pragma unroll
        for (int kb = 0; kb < 2; ++kb) {
            f32x16 s = kb ? st1 : st0;          // kb is unroll-constant
            unsigned d[8];
            #pragma unroll
            for (int j = 0; j < 8; ++j) {
                float pa = __builtin_amdgcn_exp2f(s[2 * j]);
                float pb = __builtin_amdgcn_exp2f(s[2 * j + 1]);
                d[j] = pk_bf16(pa, pb);
            }
            // redistribute across lane^32 partners:
            // new_dst = [dst_lo | src_lo], new_src = [dst_hi | src_hi]
            auto s02 = __builtin_amdgcn_permlane32_swap(d[0], d[2], false, false);
            auto s13 = __builtin_amdgcn_permlane32_swap(d[1], d[3], false, false);
            auto s46 = __builtin_amdgcn_permlane32_swap(d[4], d[6], false, false);
            auto s57 = __builtin_amdgcn_permlane32_swap(d[5], d[7], false, false);
            bf16x8 pf0 = mk8(s02[0], s13[0], s02[1], s13[1]);  // k = kb*32 + 0..15
            bf16x8 pf1 = mk8(s46[0], s57[0], s46[1], s57[1]);  // k = kb*32 + 16..31

            __builtin_amdgcn_s_setprio(1);
            lacc = __builtin_amdgcn_mfma_f32_32x32x16_bf16(pf0, ones, lacc, 0, 0, 0);
            lacc = __builtin_amdgcn_mfma_f32_32x32x16_bf16(pf1, ones, lacc, 0, 0, 0);

            bf16x8 v00 = *(const bf16x8*)&Vt[(r31)      * LSTR + kb * 32 + hi * 8];
            bf16x8 v01 = *(const bf16x8*)&Vt[(r31)      * LSTR + kb * 32 + 16 + hi * 8];
            bf16x8 v10 = *(const bf16x8*)&Vt[(32 + r31) * LSTR + kb * 32 + hi * 8];
            bf16x8 v11 = *(const bf16x8*)&Vt[(32 + r31) * LSTR + kb * 32 + 16 + hi * 8];
            oacc0 = __builtin_amdgcn_mfma_f32_32x32x16_bf16(pf0, v00, oacc0, 0, 0, 0);
            oacc0 = __builtin_amdgcn_mfma_f32_32x32x16_bf16(pf1, v01, oacc0, 0, 0, 0);
            oacc1 = __builtin_amdgcn_mfma_f32_32x32x16_bf16(pf0, v10, oacc1, 0, 0, 0);
            oacc1 = __builtin_amdgcn_mfma_f32_32x32x16_bf16(pf1, v11, oacc1, 0, 0, 0);
            __builtin_amdgcn_s_setprio(0);
        }
    }

    // oacc: O[q][d], lane holds col d = dblk*32 + (lane&31),
    // reg r -> q-row (r&3) + 8*(r>>2) + 4*hi. lacc reg r -> l[same q]. ----
    #pragma unroll
    for (int r = 0; r < 16; ++r) {
        float inv = 1.0f / lacc[r];
        int row = (r & 3) + 8 * (r >> 2) + 4 * hi;
        short* op = O + (size_t)(b * T + qw + row) * C + h * Dh + r31;
        op[0]  = f2bf(oacc0[r] * inv);
        op[32] = f2bf(oacc1[r] * inv);
    }
}

// ---------------------------------------------------------------------------
// Launch
// ---------------------------------------------------------------------------
extern "C" void kernel_launch(void* const* d_in, const int* in_sizes, int n_in,
                              void* d_out, int out_size, void* d_ws, size_t ws_size,
                              hipStream_t stream) {
    (void)in_sizes; (void)n_in; (void)out_size; (void)ws_size;

    const float* x  = (const float*)d_in[0];
    const float* Wq = (const float*)d_in[1];
    const float* bq = (const float*)d_in[2];
    const float* Wk = (const float*)d_in[3];
    const float* bk = (const float*)d_in[4];
    const float* Wv = (const float*)d_in[5];
    const float* bv = (const float*)d_in[6];
    const float* Wp = (const float*)d_in[7];
    float* out = (float*)d_out;

    short* xb    = (short*)d_ws;                 // [M][C]      bf16
    short* Wqkv  = xb + (size_t)M * C;           // [2304][768] bf16
    short* Wpb   = Wqkv + 3 * (size_t)WS2;       // [768][768]  bf16
    short* QKVb  = Wpb + (size_t)WS2;            // [M][2304]   bf16 (Q pre-scaled)
    short* AOb   = QKVb + (size_t)M * NQKV;      // [M][C]      bf16

    convert_all<<<dim3(CV_TOTAL / 1024), 256, 0, stream>>>(
        x, Wq, Wk, Wv, Wp, xb, Wqkv, Wpb);

    // Fused QKV projection: [8192 x 2304], Q columns scaled by SOFT_SCALE.
    // 1-D grid = 64 m-tiles x 18 n-tiles, XCD-slab swizzled inside.
    gemm_bt<128, 2, 2, 1, 1><<<dim3(MTILES * (NQKV / 128)), 256, 0, stream>>>(
        xb, Wqkv, bq, bk, bv, QKVb, NQKV, C);

    attn_fwd<<<dim3(T / QT, H, B), 256, 0, stream>>>(QKVb, AOb);

    // Output projection: [8192 x 768] fp32 out. 64 x 12 tiles, swizzled.
    gemm_bt<64, 4, 1, 0, 0><<<dim3(MTILES * (C / 64)), 256, 0, stream>>>(
        AOb, Wpb, nullptr, nullptr, nullptr, out, C, C);
}